// Round 14
// baseline (970.603 us; speedup 1.0000x reference)
//
#include <hip/hip_runtime.h>
#include <hip/hip_bf16.h>

#define NN 10000
#define NE 640000
#define SD 128
#define CONCAT 10003
#define ACT 10000
#define MAXDEG 256
#define GB 2500            // row-kernels (10000 waves)
#define HB 2512            // heads blocks
#define CLAIM 0x40000000u  // claim mark in cols: (v>>28)==0x4 && (v&0xFFFFFFF)<NN
#define DEGTAG 0xFFFFFFFFull

typedef unsigned int u32;
typedef unsigned short u16;
typedef unsigned long long u64;
typedef u16 u16x8 __attribute__((ext_vector_type(8)));
typedef float f32x4 __attribute__((ext_vector_type(4)));

__device__ __forceinline__ float bf2f_bits(u16 u) {
    return __uint_as_float(((u32)u) << 16);
}
__device__ __forceinline__ float loadF(const void* base, long idx, int bf) {
    if (bf) return bf2f_bits(((const u16*)base)[idx]);
    return ((const float*)base)[idx];
}
__device__ __forceinline__ int loadI(const void* base, long idx, int i64) {
    if (i64) return (int)((const long long*)base)[idx];
    return ((const int*)base)[idx];
}
__device__ __forceinline__ bool is_claimed(u32 v) {
    return ((v >> 28) == 0x4u) && ((v & 0x0FFFFFFFu) < NN);
}
__device__ __forceinline__ int degOf(const u64* __restrict__ degpack, int i) {
    u64 v = degpack[i];
    if ((u32)(v >> 32) != (u32)DEGTAG) return 0;
    int d = (int)(u32)v;
    return d > MAXDEG ? MAXDEG : d;
}

// ---- K1: probe dtypes + projection P_k = X@W1[k] + init-free CAS ELL fill.
// No intra-kernel sync needed: projection and fill are independent; fill
// requires NO pre-zeroed counters (CAS slot-claim against claim-marks; 0x00
// and 0xAA poison are both "unclaimed"). degpack via tag-guarded atomicMax.
__global__ void __launch_bounds__(256) k_prep_fill(
    const void* __restrict__ x_in, const void* __restrict__ W1,
    const void* __restrict__ Wa, const void* __restrict__ edge,
    int* __restrict__ flags, u32* __restrict__ cols, u64* __restrict__ degpack,
    float* __restrict__ P0, float* __restrict__ P1, float* __restrict__ P2) {
    __shared__ int sflags[2];
    const int tid = threadIdx.x, gid = blockIdx.x;
    const int gtid = gid * 256 + tid;
    const int lane = tid & 63;
    const int wid = gid * 4 + (tid >> 6);

    if (tid == 0) {
        const int* e32 = (const int*)edge;
        int cnt64 = 0;
        for (int e = 0; e < 64; ++e) {
            int lo = e32[2 * e], hi = e32[2 * e + 1];
            if (hi == 0 && lo >= 0 && lo < NN) cnt64++;
        }
        sflags[0] = (cnt64 >= 56) ? 1 : 0;
        const u32* w = (const u32*)Wa;
        int c = 0;
        for (int j = 0; j < 256; ++j) {
            u32 lo = w[j] & 0xFFFFu;
            int ex = (int)((lo >> 7) & 0xFF);
            if (ex >= 100 && ex <= 140) c++;
        }
        sflags[1] = (c >= 128) ? 1 : 0;
        if (gid == 0) {
            flags[0] = sflags[0];
            flags[1] = sflags[1];
        }
    }
    __syncthreads();
    const int i64f = sflags[0], bf = sflags[1];

    // projection P_k = X @ W1[k]
    {
        int o = lane < 60 ? lane : 59;
        for (int r = wid; r < NN; r += GB * 4) {
            float xa, xb;
            if (bf) {
                u32 wbits = ((const u32*)x_in)[(long)r * 64 + lane];
                xa = bf2f_bits((u16)(wbits & 0xFFFFu));
                xb = bf2f_bits((u16)(wbits >> 16));
            } else {
                const float* xp = (const float*)x_in + (long)r * SD + 2 * lane;
                xa = xp[0];
                xb = xp[1];
            }
            float a0 = 0.f, a1 = 0.f, a2 = 0.f;
            for (int j2 = 0; j2 < 64; ++j2) {
                float xe = __shfl(xa, j2);
                float xo = __shfl(xb, j2);
                long je = (long)(2 * j2) * 60 + o;
                long jo = (long)(2 * j2 + 1) * 60 + o;
                a0 += xe * loadF(W1, 0 * SD * 60 + je, bf) + xo * loadF(W1, 0 * SD * 60 + jo, bf);
                a1 += xe * loadF(W1, 1 * SD * 60 + je, bf) + xo * loadF(W1, 1 * SD * 60 + jo, bf);
                a2 += xe * loadF(W1, 2 * SD * 60 + je, bf) + xo * loadF(W1, 2 * SD * 60 + jo, bf);
            }
            if (lane < 60) {
                P0[(long)r * 60 + lane] = a0;
                P1[(long)r * 60 + lane] = a1;
                P2[(long)r * 60 + lane] = a2;
            }
        }
    }

    // init-free ELL fill: claim first unclaimed slot in dst row
    for (int e = gtid; e < NE; e += GB * 256) {
        int s = loadI(edge, e, i64f);
        int d = loadI(edge, NE + e, i64f);
        u32* row = cols + (size_t)d * MAXDEG;
        u32 mark = CLAIM | (u32)s;
        for (int slot = 0; slot < MAXDEG; ++slot) {
            u32 v = __hip_atomic_load(&row[slot], __ATOMIC_RELAXED, __HIP_MEMORY_SCOPE_AGENT);
            if (is_claimed(v)) continue;
            u32 got = atomicCAS(&row[slot], v, mark);
            if (got == v) {
                atomicMax(&degpack[d], (DEGTAG << 32) | (u64)(slot + 1));
                break;
            }
            // got != v -> slot was just claimed by another edge; move on
        }
    }
}

// ---- k_s1: U = Lhat P2 (compute + cache weights) ; W60 = P1 + 2U ----
__global__ void __launch_bounds__(256) k_s1(
    const u64* __restrict__ degpack, const u32* __restrict__ cols,
    float* __restrict__ wve, const float* __restrict__ P1,
    const float* __restrict__ P2, float* __restrict__ W60) {
    const int tid = threadIdx.x;
    const int lane = tid & 63;
    const int wid = blockIdx.x * 4 + (tid >> 6);
    int o = lane < 60 ? lane : 59;
    for (int r = wid; r < NN; r += GB * 4) {
        int cr = degOf(degpack, r);
        float rr = cr > 0 ? rsqrtf((float)cr) : 0.f;
        const u32* cp = cols + (size_t)r * MAXDEG;
        float* wp = wve + (size_t)r * MAXDEG;
        float acc = 0.f;
        int p = 0;
        for (; p + 3 < cr; p += 4) {
            int s0 = cp[p] & 0x0FFFFFFF, s1 = cp[p + 1] & 0x0FFFFFFF;
            int s2 = cp[p + 2] & 0x0FFFFFFF, s3 = cp[p + 3] & 0x0FFFFFFF;
            int c0 = degOf(degpack, s0), c1 = degOf(degpack, s1);
            int c2 = degOf(degpack, s2), c3 = degOf(degpack, s3);
            float w0 = c0 > 0 ? -rsqrtf((float)c0) * rr : 0.f;
            float w1 = c1 > 0 ? -rsqrtf((float)c1) * rr : 0.f;
            float w2 = c2 > 0 ? -rsqrtf((float)c2) * rr : 0.f;
            float w3 = c3 > 0 ? -rsqrtf((float)c3) * rr : 0.f;
            acc += w0 * P2[(size_t)s0 * 60 + o] + w1 * P2[(size_t)s1 * 60 + o] +
                   w2 * P2[(size_t)s2 * 60 + o] + w3 * P2[(size_t)s3 * 60 + o];
            if (lane == 63) {
                wp[p] = w0;
                wp[p + 1] = w1;
                wp[p + 2] = w2;
                wp[p + 3] = w3;
            }
        }
        for (; p < cr; ++p) {
            int s = cp[p] & 0x0FFFFFFF;
            int cs = degOf(degpack, s);
            float w = cs > 0 ? -rsqrtf((float)cs) * rr : 0.f;
            acc += w * P2[(size_t)s * 60 + o];
            if (lane == 63) wp[p] = w;
        }
        if (lane < 60)
            W60[(size_t)r * 60 + lane] = P1[(size_t)r * 60 + lane] + 2.f * acc;
    }
}

// ---- k_s2: V = Lhat W60 ; h1 = tanh(P0-P2+V+b1) ; Q_k = h1 @ W2[k] ----
__global__ void __launch_bounds__(256) k_s2(
    const u64* __restrict__ degpack, const u32* __restrict__ cols,
    const float* __restrict__ wve, const float* __restrict__ P0,
    const float* __restrict__ P2, const float* __restrict__ W60,
    const void* __restrict__ W2, const void* __restrict__ b1,
    const int* __restrict__ flags, float* __restrict__ Q0,
    float* __restrict__ Q1, float* __restrict__ Q2) {
    const int bf = flags[1];
    const int tid = threadIdx.x;
    const int lane = tid & 63;
    const int wid = blockIdx.x * 4 + (tid >> 6);
    int o = lane < 60 ? lane : 59;
    int o2 = lane < 30 ? lane : 29;
    for (int r = wid; r < NN; r += GB * 4) {
        int cr = degOf(degpack, r);
        const u32* cp = cols + (size_t)r * MAXDEG;
        const float* wp = wve + (size_t)r * MAXDEG;
        float acc = 0.f;
        int p = 0;
        for (; p + 3 < cr; p += 4) {
            acc += wp[p] * W60[(size_t)(cp[p] & 0x0FFFFFFF) * 60 + o] +
                   wp[p + 1] * W60[(size_t)(cp[p + 1] & 0x0FFFFFFF) * 60 + o] +
                   wp[p + 2] * W60[(size_t)(cp[p + 2] & 0x0FFFFFFF) * 60 + o] +
                   wp[p + 3] * W60[(size_t)(cp[p + 3] & 0x0FFFFFFF) * 60 + o];
        }
        for (; p < cr; ++p) acc += wp[p] * W60[(size_t)(cp[p] & 0x0FFFFFFF) * 60 + o];
        float h1 = tanhf(P0[(size_t)r * 60 + o] - P2[(size_t)r * 60 + o] + acc +
                         loadF(b1, o, bf));
        float q0 = 0.f, q1 = 0.f, q2 = 0.f;
        for (int j = 0; j < 60; ++j) {
            float xj = __shfl(h1, j);
            long idx = (long)j * 30 + o2;
            q0 += xj * loadF(W2, 0 * 60 * 30 + idx, bf);
            q1 += xj * loadF(W2, 1 * 60 * 30 + idx, bf);
            q2 += xj * loadF(W2, 2 * 60 * 30 + idx, bf);
        }
        if (lane < 30) {
            Q0[(size_t)r * 30 + lane] = q0;
            Q1[(size_t)r * 30 + lane] = q1;
            Q2[(size_t)r * 30 + lane] = q2;
        }
    }
}

// ---- k_s3: U2 = Lhat Q2 ; W30 = Q1 + 2U2 ----
__global__ void __launch_bounds__(256) k_s3(
    const u64* __restrict__ degpack, const u32* __restrict__ cols,
    const float* __restrict__ wve, const float* __restrict__ Q1,
    const float* __restrict__ Q2, float* __restrict__ W30) {
    const int tid = threadIdx.x;
    const int lane = tid & 63;
    const int wid = blockIdx.x * 4 + (tid >> 6);
    int h = lane >> 5, l = lane & 31;
    int l2 = l < 30 ? l : 29;
    for (int r = wid; r < NN; r += GB * 4) {
        int cr = degOf(degpack, r);
        const u32* cp = cols + (size_t)r * MAXDEG;
        const float* wp = wve + (size_t)r * MAXDEG;
        float acc = 0.f;
        for (int p = h; p < cr; p += 2)
            acc += wp[p] * Q2[(size_t)(cp[p] & 0x0FFFFFFF) * 30 + l2];
        acc += __shfl_xor(acc, 32);
        if (lane < 30)
            W30[(size_t)r * 30 + lane] = Q1[(size_t)r * 30 + lane] + 2.f * acc;
    }
}

// ---- k_s4: V2 = Lhat W30 ; h2 = tanh(Q0-Q2+V2+b2) ; R_k = h2 . W3[k] ----
__global__ void __launch_bounds__(256) k_s4(
    const u64* __restrict__ degpack, const u32* __restrict__ cols,
    const float* __restrict__ wve, const float* __restrict__ Q0,
    const float* __restrict__ Q2, const float* __restrict__ W30,
    const void* __restrict__ W3, const void* __restrict__ b2,
    const int* __restrict__ flags, float* __restrict__ R1,
    float* __restrict__ R2, float* __restrict__ Sa) {
    const int bf = flags[1];
    const int tid = threadIdx.x;
    const int lane = tid & 63;
    const int wid = blockIdx.x * 4 + (tid >> 6);
    int h = lane >> 5, l = lane & 31;
    int l2 = l < 30 ? l : 29;
    for (int r = wid; r < NN; r += GB * 4) {
        int cr = degOf(degpack, r);
        const u32* cp = cols + (size_t)r * MAXDEG;
        const float* wp = wve + (size_t)r * MAXDEG;
        float acc = 0.f;
        for (int p = h; p < cr; p += 2)
            acc += wp[p] * W30[(size_t)(cp[p] & 0x0FFFFFFF) * 30 + l2];
        acc += __shfl_xor(acc, 32);
        float r0 = 0.f, r1 = 0.f, r2 = 0.f;
        if (l < 30) {
            float h2v = tanhf(Q0[(size_t)r * 30 + l] - Q2[(size_t)r * 30 + l] + acc +
                              loadF(b2, l, bf));
            r0 = h2v * loadF(W3, 0 * 30 + l, bf);
            r1 = h2v * loadF(W3, 1 * 30 + l, bf);
            r2 = h2v * loadF(W3, 2 * 30 + l, bf);
        }
#pragma unroll
        for (int m = 16; m; m >>= 1) {
            r0 += __shfl_xor(r0, m);
            r1 += __shfl_xor(r1, m);
            r2 += __shfl_xor(r2, m);
        }
        if (lane == 0) {
            R1[r] = r1;
            R2[r] = r2;
            Sa[r] = r0 - r2;
        }
    }
}

// ---- k_s5: U3 = Lhat R2 ; Wv3 = R1 + 2U3 ----
__global__ void __launch_bounds__(256) k_s5(
    const u64* __restrict__ degpack, const u32* __restrict__ cols,
    const float* __restrict__ wve, const float* __restrict__ R1,
    const float* __restrict__ R2, float* __restrict__ Wv3) {
    const int tid = threadIdx.x;
    const int lane = tid & 63;
    const int wid = blockIdx.x * 4 + (tid >> 6);
    for (int r = wid; r < NN; r += GB * 4) {
        int cr = degOf(degpack, r);
        const u32* cp = cols + (size_t)r * MAXDEG;
        const float* wp = wve + (size_t)r * MAXDEG;
        float acc = 0.f;
        for (int p = lane; p < cr; p += 64) acc += wp[p] * R2[cp[p] & 0x0FFFFFFF];
#pragma unroll
        for (int m = 32; m; m >>= 1) acc += __shfl_xor(acc, m);
        if (lane == 0) Wv3[r] = R1[r] + 2.f * acc;
    }
}

// ---- k_s6: V3 = Lhat Wv3 ; state = tanh(Sa+V3+b3) ; tail scalars ----
__global__ void __launch_bounds__(256) k_s6(
    const u64* __restrict__ degpack, const u32* __restrict__ cols,
    const float* __restrict__ wve, const float* __restrict__ Sa,
    const float* __restrict__ Wv3, const void* __restrict__ b3,
    const void* sc0, const void* sc1, const void* sc2,
    const int* __restrict__ flags, float* __restrict__ state) {
    const int bf = flags[1];
    const int tid = threadIdx.x;
    const int lane = tid & 63;
    const int wid = blockIdx.x * 4 + (tid >> 6);
    for (int r = wid; r < NN; r += GB * 4) {
        int cr = degOf(degpack, r);
        const u32* cp = cols + (size_t)r * MAXDEG;
        const float* wp = wve + (size_t)r * MAXDEG;
        float acc = 0.f;
        for (int p = lane; p < cr; p += 64) acc += wp[p] * Wv3[cp[p] & 0x0FFFFFFF];
#pragma unroll
        for (int m = 32; m; m >>= 1) acc += __shfl_xor(acc, m);
        if (lane == 0) state[r] = tanhf(Sa[r] + acc + loadF(b3, 0, bf));
    }
    if (blockIdx.x == 0 && tid == 0) {
        state[10000] = loadF(sc0, 0, bf);
        state[10001] = loadF(sc1, 0, bf);
        state[10002] = loadF(sc2, 0, bf);
    }
}

// ---- k_heads: wave per row; resets cols/degpack for next replay ----
__global__ void __launch_bounds__(256) k_heads(
    const float* __restrict__ state, const void* __restrict__ Wa,
    const void* __restrict__ ba, const void* __restrict__ Wc,
    const void* __restrict__ bc, const int* __restrict__ flags,
    u32* __restrict__ cols, u64* __restrict__ degpack, void* __restrict__ out) {
    const int bf = flags[1];
    const int tid = threadIdx.x;
    const int lane = tid & 63;
    const int wid = blockIdx.x * 4 + (tid >> 6);
    // reset claim-marks + degrees (nothing reads them again until next run's K1)
    for (int i = blockIdx.x * 256 + tid; i < NN * MAXDEG; i += HB * 256) cols[i] = 0u;
    for (int i = blockIdx.x * 256 + tid; i < NN; i += HB * 256) degpack[i] = 0ull;
    for (int r = wid; r <= ACT; r += HB * 4) {
        long base = (r < ACT) ? (long)r * CONCAT : 0;
        const void* wb = (r < ACT) ? Wa : Wc;
        float acc = 0.f;
        if (bf) {
            const u16* w = (const u16*)wb + base;
            int k = (int)((16 - ((2 * base) & 15)) & 15) >> 1;
            for (int i = lane; i < k; i += 64) acc += state[i] * bf2f_bits(w[i]);
            int nv = (CONCAT - k) >> 3;
            const u16x8* wvp = (const u16x8*)(w + k);
            for (int v = lane; v < nv; v += 64) {
                u16x8 ww = wvp[v];
                int ib = k + v * 8;
#pragma unroll
                for (int j = 0; j < 8; ++j) acc += state[ib + j] * bf2f_bits(ww[j]);
            }
            for (int i = k + nv * 8 + lane; i < CONCAT; i += 64)
                acc += state[i] * bf2f_bits(w[i]);
        } else {
            const float* w = (const float*)wb + base;
            int k = (int)((16 - ((4 * base) & 15)) & 15) >> 2;
            for (int i = lane; i < k; i += 64) acc += state[i] * w[i];
            int nv = (CONCAT - k) >> 2;
            const f32x4* wvp = (const f32x4*)(w + k);
            for (int v = lane; v < nv; v += 64) {
                f32x4 ww = wvp[v];
                int ib = k + v * 4;
#pragma unroll
                for (int j = 0; j < 4; ++j) acc += state[ib + j] * ww[j];
            }
            for (int i = k + nv * 4 + lane; i < CONCAT; i += 64)
                acc += state[i] * w[i];
        }
#pragma unroll
        for (int o = 32; o > 0; o >>= 1) acc += __shfl_xor(acc, o);
        if (lane == 0) {
            float bias = (r < ACT) ? loadF(ba, r, bf) : loadF(bc, 0, bf);
            float v = acc + bias;
            if (bf) ((__hip_bfloat16*)out)[r] = __float2bfloat16(v);
            else ((float*)out)[r] = v;
        }
    }
}

extern "C" void kernel_launch(void* const* d_in, const int* in_sizes, int n_in,
                              void* d_out, int out_size, void* d_ws, size_t ws_size,
                              hipStream_t stream) {
    const void* x_in = d_in[0];
    const void* edge = d_in[1];
    const void* sc0 = d_in[2];
    const void* sc1 = d_in[3];
    const void* sc2 = d_in[4];
    const void* W1 = d_in[5];
    const void* b1 = d_in[6];
    const void* W2 = d_in[7];
    const void* b2 = d_in[8];
    const void* W3 = d_in[9];
    const void* b3 = d_in[10];
    const void* Wa = d_in[11];
    const void* ba = d_in[12];
    const void* Wc = d_in[13];
    const void* bc = d_in[14];

    char* p = (char*)d_ws;
    auto alloc = [&](size_t bytes) {
        char* r = p;
        p += (bytes + 255) & ~(size_t)255;
        return (void*)r;
    };
    int* flags = (int*)alloc(2 * 4);
    u32* cols = (u32*)alloc((size_t)NN * MAXDEG * 4);
    u64* degpack = (u64*)alloc((size_t)NN * 8);
    float* wve = (float*)alloc((size_t)NN * MAXDEG * 4);
    float* P0 = (float*)alloc((size_t)NN * 60 * 4);
    float* P1 = (float*)alloc((size_t)NN * 60 * 4);
    float* P2 = (float*)alloc((size_t)NN * 60 * 4);
    float* W60 = (float*)alloc((size_t)NN * 60 * 4);
    float* Q0 = (float*)alloc((size_t)NN * 30 * 4);
    float* Q1 = (float*)alloc((size_t)NN * 30 * 4);
    float* Q2 = (float*)alloc((size_t)NN * 30 * 4);
    float* W30 = (float*)alloc((size_t)NN * 30 * 4);
    float* R1 = (float*)alloc(NN * 4);
    float* R2 = (float*)alloc(NN * 4);
    float* Sa = (float*)alloc(NN * 4);
    float* Wv3 = (float*)alloc(NN * 4);
    float* state = (float*)alloc(CONCAT * 4);

    k_prep_fill<<<GB, 256, 0, stream>>>(x_in, W1, Wa, edge, flags, cols, degpack,
                                        P0, P1, P2);
    k_s1<<<GB, 256, 0, stream>>>(degpack, cols, wve, P1, P2, W60);
    k_s2<<<GB, 256, 0, stream>>>(degpack, cols, wve, P0, P2, W60, W2, b1, flags, Q0, Q1, Q2);
    k_s3<<<GB, 256, 0, stream>>>(degpack, cols, wve, Q1, Q2, W30);
    k_s4<<<GB, 256, 0, stream>>>(degpack, cols, wve, Q0, Q2, W30, W3, b2, flags, R1, R2, Sa);
    k_s5<<<GB, 256, 0, stream>>>(degpack, cols, wve, R1, R2, Wv3);
    k_s6<<<GB, 256, 0, stream>>>(degpack, cols, wve, Sa, Wv3, b3, sc0, sc1, sc2, flags, state);
    k_heads<<<HB, 256, 0, stream>>>(state, Wa, ba, Wc, bc, flags, cols, degpack, d_out);
}

// Round 15
// 344.930 us; speedup vs baseline: 2.8139x; 2.8139x over previous
//
#include <hip/hip_runtime.h>
#include <hip/hip_bf16.h>

#define NN 10000
#define NE 640000
#define SD 128
#define CONCAT 10003
#define ACT 10000
#define MAXDEG 256
#define GB 2500            // row-kernels (10000 waves)
#define HB 2512            // heads blocks

typedef unsigned int u32;
typedef unsigned short u16;
typedef u16 u16x8 __attribute__((ext_vector_type(8)));
typedef float f32x4 __attribute__((ext_vector_type(4)));

__device__ __forceinline__ float bf2f_bits(u16 u) {
    return __uint_as_float(((u32)u) << 16);
}
__device__ __forceinline__ u16 f2b(float x) {  // round-to-nearest-even f32 -> bf16
    u32 u = __float_as_uint(x);
    u32 r = (u + 0x7FFFu + ((u >> 16) & 1u)) >> 16;
    return (u16)r;
}
__device__ __forceinline__ float loadF(const void* base, long idx, int bf) {
    if (bf) return bf2f_bits(((const u16*)base)[idx]);
    return ((const float*)base)[idx];
}
__device__ __forceinline__ int loadI(const void* base, long idx, int i64) {
    if (i64) return (int)((const long long*)base)[idx];
    return ((const int*)base)[idx];
}

// ---- k_prep: probe dtypes (block0 -> flags), zero cnt, P_k = X@W1[k].
// P0,P1 stay f32 (row-local streams); P2 stored bf16 (it is GATHERED in s1). ----
__global__ void __launch_bounds__(256) k_prep(
    const void* __restrict__ x_in, const void* __restrict__ W1,
    const void* __restrict__ Wa, const void* __restrict__ edge,
    int* __restrict__ flags, int* __restrict__ cnt,
    float* __restrict__ P0, float* __restrict__ P1, u16* __restrict__ P2b) {
    __shared__ int sbf;
    const int tid = threadIdx.x, gid = blockIdx.x;
    const int gtid = gid * 256 + tid;
    const int lane = tid & 63;
    const int wid = gid * 4 + (tid >> 6);

    if (tid == 0) {
        const u32* w = (const u32*)Wa;
        int c = 0;
        for (int j = 0; j < 256; ++j) {
            u32 lo = w[j] & 0xFFFFu;
            int ex = (int)((lo >> 7) & 0xFF);
            if (ex >= 100 && ex <= 140) c++;
        }
        sbf = (c >= 128) ? 1 : 0;
        if (gid == 0) {
            const int* e32 = (const int*)edge;
            int cnt64 = 0;
            for (int e = 0; e < 64; ++e) {
                int lo = e32[2 * e], hi = e32[2 * e + 1];
                if (hi == 0 && lo >= 0 && lo < NN) cnt64++;
            }
            flags[0] = (cnt64 >= 56) ? 1 : 0;
            flags[1] = sbf;
        }
    }
    __syncthreads();
    const int bf = sbf;

    for (int i = gtid; i < NN; i += GB * 256) cnt[i] = 0;

    int o = lane < 60 ? lane : 59;
    for (int r = wid; r < NN; r += GB * 4) {
        float xa, xb;
        if (bf) {
            u32 wbits = ((const u32*)x_in)[(long)r * 64 + lane];
            xa = bf2f_bits((u16)(wbits & 0xFFFFu));
            xb = bf2f_bits((u16)(wbits >> 16));
        } else {
            const float* xp = (const float*)x_in + (long)r * SD + 2 * lane;
            xa = xp[0];
            xb = xp[1];
        }
        float a0 = 0.f, a1 = 0.f, a2 = 0.f;
        for (int j2 = 0; j2 < 64; ++j2) {
            float xe = __shfl(xa, j2);
            float xo = __shfl(xb, j2);
            long je = (long)(2 * j2) * 60 + o;
            long jo = (long)(2 * j2 + 1) * 60 + o;
            a0 += xe * loadF(W1, 0 * SD * 60 + je, bf) + xo * loadF(W1, 0 * SD * 60 + jo, bf);
            a1 += xe * loadF(W1, 1 * SD * 60 + je, bf) + xo * loadF(W1, 1 * SD * 60 + jo, bf);
            a2 += xe * loadF(W1, 2 * SD * 60 + je, bf) + xo * loadF(W1, 2 * SD * 60 + jo, bf);
        }
        if (lane < 60) {
            P0[(long)r * 60 + lane] = a0;
            P1[(long)r * 60 + lane] = a1;
            P2b[(long)r * 60 + lane] = f2b(a2);
        }
    }
}

// ---- k_fill: ELL fill; cnt becomes in-degree ----
__global__ void __launch_bounds__(256) k_fill(
    const void* __restrict__ edge, const int* __restrict__ flags,
    int* __restrict__ cnt, int* __restrict__ cols) {
    const int i64f = flags[0];
    int e = blockIdx.x * 256 + threadIdx.x;
    for (; e < NE; e += GB * 256) {
        int s = loadI(edge, e, i64f);
        int d = loadI(edge, NE + e, i64f);
        int pos = atomicAdd(&cnt[d], 1);
        if (pos < MAXDEG) cols[(size_t)d * MAXDEG + pos] = s;
    }
}

// ---- k_s1: U = Lhat P2 (gather bf16; compute + cache weights f32) ; W60 = P1 + 2U (bf16 out) ----
__global__ void __launch_bounds__(256) k_s1(
    const int* __restrict__ cnt, const int* __restrict__ cols,
    float* __restrict__ wve, const float* __restrict__ P1,
    const u16* __restrict__ P2b, u16* __restrict__ W60b) {
    const int tid = threadIdx.x;
    const int lane = tid & 63;
    const int wid = blockIdx.x * 4 + (tid >> 6);
    int o = lane < 60 ? lane : 59;
    for (int r = wid; r < NN; r += GB * 4) {
        int cr = cnt[r];
        if (cr > MAXDEG) cr = MAXDEG;
        float rr = cr > 0 ? rsqrtf((float)cr) : 0.f;
        const int* cp = cols + (size_t)r * MAXDEG;
        float* wp = wve + (size_t)r * MAXDEG;
        float acc = 0.f;
        int p = 0;
        for (; p + 3 < cr; p += 4) {
            int s0 = cp[p], s1 = cp[p + 1], s2 = cp[p + 2], s3 = cp[p + 3];
            int c0 = cnt[s0], c1 = cnt[s1], c2 = cnt[s2], c3 = cnt[s3];
            float w0 = c0 > 0 ? -rsqrtf((float)c0) * rr : 0.f;
            float w1 = c1 > 0 ? -rsqrtf((float)c1) * rr : 0.f;
            float w2 = c2 > 0 ? -rsqrtf((float)c2) * rr : 0.f;
            float w3 = c3 > 0 ? -rsqrtf((float)c3) * rr : 0.f;
            acc += w0 * bf2f_bits(P2b[(size_t)s0 * 60 + o]) +
                   w1 * bf2f_bits(P2b[(size_t)s1 * 60 + o]) +
                   w2 * bf2f_bits(P2b[(size_t)s2 * 60 + o]) +
                   w3 * bf2f_bits(P2b[(size_t)s3 * 60 + o]);
            if (lane == 63) {
                wp[p] = w0;
                wp[p + 1] = w1;
                wp[p + 2] = w2;
                wp[p + 3] = w3;
            }
        }
        for (; p < cr; ++p) {
            int s = cp[p];
            int cs = cnt[s];
            float w = cs > 0 ? -rsqrtf((float)cs) * rr : 0.f;
            acc += w * bf2f_bits(P2b[(size_t)s * 60 + o]);
            if (lane == 63) wp[p] = w;
        }
        if (lane < 60)
            W60b[(size_t)r * 60 + lane] = f2b(P1[(size_t)r * 60 + lane] + 2.f * acc);
    }
}

// ---- k_s2: V = Lhat W60 (gather bf16) ; h1 = tanh(P0-P2+V+b1) ; Q_k = h1 @ W2[k] ----
__global__ void __launch_bounds__(256) k_s2(
    const int* __restrict__ cnt, const int* __restrict__ cols,
    const float* __restrict__ wve, const float* __restrict__ P0,
    const u16* __restrict__ P2b, const u16* __restrict__ W60b,
    const void* __restrict__ W2, const void* __restrict__ b1,
    const int* __restrict__ flags, float* __restrict__ Q0,
    float* __restrict__ Q1, u16* __restrict__ Q2b) {
    const int bf = flags[1];
    const int tid = threadIdx.x;
    const int lane = tid & 63;
    const int wid = blockIdx.x * 4 + (tid >> 6);
    int o = lane < 60 ? lane : 59;
    int o2 = lane < 30 ? lane : 29;
    for (int r = wid; r < NN; r += GB * 4) {
        int cr = cnt[r];
        if (cr > MAXDEG) cr = MAXDEG;
        const int* cp = cols + (size_t)r * MAXDEG;
        const float* wp = wve + (size_t)r * MAXDEG;
        float acc = 0.f;
        int p = 0;
        for (; p + 3 < cr; p += 4) {
            acc += wp[p] * bf2f_bits(W60b[(size_t)cp[p] * 60 + o]) +
                   wp[p + 1] * bf2f_bits(W60b[(size_t)cp[p + 1] * 60 + o]) +
                   wp[p + 2] * bf2f_bits(W60b[(size_t)cp[p + 2] * 60 + o]) +
                   wp[p + 3] * bf2f_bits(W60b[(size_t)cp[p + 3] * 60 + o]);
        }
        for (; p < cr; ++p) acc += wp[p] * bf2f_bits(W60b[(size_t)cp[p] * 60 + o]);
        float h1 = tanhf(P0[(size_t)r * 60 + o] - bf2f_bits(P2b[(size_t)r * 60 + o]) +
                         acc + loadF(b1, o, bf));
        float q0 = 0.f, q1 = 0.f, q2 = 0.f;
        for (int j = 0; j < 60; ++j) {
            float xj = __shfl(h1, j);
            long idx = (long)j * 30 + o2;
            q0 += xj * loadF(W2, 0 * 60 * 30 + idx, bf);
            q1 += xj * loadF(W2, 1 * 60 * 30 + idx, bf);
            q2 += xj * loadF(W2, 2 * 60 * 30 + idx, bf);
        }
        if (lane < 30) {
            Q0[(size_t)r * 30 + lane] = q0;
            Q1[(size_t)r * 30 + lane] = q1;
            Q2b[(size_t)r * 30 + lane] = f2b(q2);
        }
    }
}

// ---- k_s3: U2 = Lhat Q2 (gather bf16) ; W30 = Q1 + 2U2 (bf16 out) ----
__global__ void __launch_bounds__(256) k_s3(
    const int* __restrict__ cnt, const int* __restrict__ cols,
    const float* __restrict__ wve, const float* __restrict__ Q1,
    const u16* __restrict__ Q2b, u16* __restrict__ W30b) {
    const int tid = threadIdx.x;
    const int lane = tid & 63;
    const int wid = blockIdx.x * 4 + (tid >> 6);
    int h = lane >> 5, l = lane & 31;
    int l2 = l < 30 ? l : 29;
    for (int r = wid; r < NN; r += GB * 4) {
        int cr = cnt[r];
        if (cr > MAXDEG) cr = MAXDEG;
        const int* cp = cols + (size_t)r * MAXDEG;
        const float* wp = wve + (size_t)r * MAXDEG;
        float acc = 0.f;
        for (int p = h; p < cr; p += 2)
            acc += wp[p] * bf2f_bits(Q2b[(size_t)cp[p] * 30 + l2]);
        acc += __shfl_xor(acc, 32);
        if (lane < 30)
            W30b[(size_t)r * 30 + lane] = f2b(Q1[(size_t)r * 30 + lane] + 2.f * acc);
    }
}

// ---- k_s4: V2 = Lhat W30 (gather bf16) ; h2 = tanh(Q0-Q2+V2+b2) ; R_k = h2 . W3[k] ----
__global__ void __launch_bounds__(256) k_s4(
    const int* __restrict__ cnt, const int* __restrict__ cols,
    const float* __restrict__ wve, const float* __restrict__ Q0,
    const u16* __restrict__ Q2b, const u16* __restrict__ W30b,
    const void* __restrict__ W3, const void* __restrict__ b2,
    const int* __restrict__ flags, float* __restrict__ R1,
    float* __restrict__ R2, float* __restrict__ Sa) {
    const int bf = flags[1];
    const int tid = threadIdx.x;
    const int lane = tid & 63;
    const int wid = blockIdx.x * 4 + (tid >> 6);
    int h = lane >> 5, l = lane & 31;
    int l2 = l < 30 ? l : 29;
    for (int r = wid; r < NN; r += GB * 4) {
        int cr = cnt[r];
        if (cr > MAXDEG) cr = MAXDEG;
        const int* cp = cols + (size_t)r * MAXDEG;
        const float* wp = wve + (size_t)r * MAXDEG;
        float acc = 0.f;
        for (int p = h; p < cr; p += 2)
            acc += wp[p] * bf2f_bits(W30b[(size_t)cp[p] * 30 + l2]);
        acc += __shfl_xor(acc, 32);
        float r0 = 0.f, r1 = 0.f, r2 = 0.f;
        if (l < 30) {
            float h2v = tanhf(Q0[(size_t)r * 30 + l] - bf2f_bits(Q2b[(size_t)r * 30 + l]) +
                              acc + loadF(b2, l, bf));
            r0 = h2v * loadF(W3, 0 * 30 + l, bf);
            r1 = h2v * loadF(W3, 1 * 30 + l, bf);
            r2 = h2v * loadF(W3, 2 * 30 + l, bf);
        }
#pragma unroll
        for (int m = 16; m; m >>= 1) {
            r0 += __shfl_xor(r0, m);
            r1 += __shfl_xor(r1, m);
            r2 += __shfl_xor(r2, m);
        }
        if (lane == 0) {
            R1[r] = r1;
            R2[r] = r2;
            Sa[r] = r0 - r2;
        }
    }
}

// ---- k_s5: U3 = Lhat R2 ; Wv3 = R1 + 2U3 ----
__global__ void __launch_bounds__(256) k_s5(
    const int* __restrict__ cnt, const int* __restrict__ cols,
    const float* __restrict__ wve, const float* __restrict__ R1,
    const float* __restrict__ R2, float* __restrict__ Wv3) {
    const int tid = threadIdx.x;
    const int lane = tid & 63;
    const int wid = blockIdx.x * 4 + (tid >> 6);
    for (int r = wid; r < NN; r += GB * 4) {
        int cr = cnt[r];
        if (cr > MAXDEG) cr = MAXDEG;
        const int* cp = cols + (size_t)r * MAXDEG;
        const float* wp = wve + (size_t)r * MAXDEG;
        float acc = 0.f;
        for (int p = lane; p < cr; p += 64) acc += wp[p] * R2[cp[p]];
#pragma unroll
        for (int m = 32; m; m >>= 1) acc += __shfl_xor(acc, m);
        if (lane == 0) Wv3[r] = R1[r] + 2.f * acc;
    }
}

// ---- k_s6: V3 = Lhat Wv3 ; state = tanh(Sa+V3+b3) ; tail scalars ----
__global__ void __launch_bounds__(256) k_s6(
    const int* __restrict__ cnt, const int* __restrict__ cols,
    const float* __restrict__ wve, const float* __restrict__ Sa,
    const float* __restrict__ Wv3, const void* __restrict__ b3,
    const void* sc0, const void* sc1, const void* sc2,
    const int* __restrict__ flags, float* __restrict__ state) {
    const int bf = flags[1];
    const int tid = threadIdx.x;
    const int lane = tid & 63;
    const int wid = blockIdx.x * 4 + (tid >> 6);
    for (int r = wid; r < NN; r += GB * 4) {
        int cr = cnt[r];
        if (cr > MAXDEG) cr = MAXDEG;
        const int* cp = cols + (size_t)r * MAXDEG;
        const float* wp = wve + (size_t)r * MAXDEG;
        float acc = 0.f;
        for (int p = lane; p < cr; p += 64) acc += wp[p] * Wv3[cp[p]];
#pragma unroll
        for (int m = 32; m; m >>= 1) acc += __shfl_xor(acc, m);
        if (lane == 0) state[r] = tanhf(Sa[r] + acc + loadF(b3, 0, bf));
    }
    if (blockIdx.x == 0 && tid == 0) {
        state[10000] = loadF(sc0, 0, bf);
        state[10001] = loadF(sc1, 0, bf);
        state[10002] = loadF(sc2, 0, bf);
    }
}

// ---- k_heads: wave per row ----
__global__ void __launch_bounds__(256) k_heads(
    const float* __restrict__ state, const void* __restrict__ Wa,
    const void* __restrict__ ba, const void* __restrict__ Wc,
    const void* __restrict__ bc, const int* __restrict__ flags,
    void* __restrict__ out) {
    const int bf = flags[1];
    const int tid = threadIdx.x;
    const int lane = tid & 63;
    const int wid = blockIdx.x * 4 + (tid >> 6);
    for (int r = wid; r <= ACT; r += HB * 4) {
        long base = (r < ACT) ? (long)r * CONCAT : 0;
        const void* wb = (r < ACT) ? Wa : Wc;
        float acc = 0.f;
        if (bf) {
            const u16* w = (const u16*)wb + base;
            int k = (int)((16 - ((2 * base) & 15)) & 15) >> 1;
            for (int i = lane; i < k; i += 64) acc += state[i] * bf2f_bits(w[i]);
            int nv = (CONCAT - k) >> 3;
            const u16x8* wvp = (const u16x8*)(w + k);
            for (int v = lane; v < nv; v += 64) {
                u16x8 ww = wvp[v];
                int ib = k + v * 8;
#pragma unroll
                for (int j = 0; j < 8; ++j) acc += state[ib + j] * bf2f_bits(ww[j]);
            }
            for (int i = k + nv * 8 + lane; i < CONCAT; i += 64)
                acc += state[i] * bf2f_bits(w[i]);
        } else {
            const float* w = (const float*)wb + base;
            int k = (int)((16 - ((4 * base) & 15)) & 15) >> 2;
            for (int i = lane; i < k; i += 64) acc += state[i] * w[i];
            int nv = (CONCAT - k) >> 2;
            const f32x4* wvp = (const f32x4*)(w + k);
            for (int v = lane; v < nv; v += 64) {
                f32x4 ww = wvp[v];
                int ib = k + v * 4;
#pragma unroll
                for (int j = 0; j < 4; ++j) acc += state[ib + j] * ww[j];
            }
            for (int i = k + nv * 4 + lane; i < CONCAT; i += 64)
                acc += state[i] * w[i];
        }
#pragma unroll
        for (int o = 32; o > 0; o >>= 1) acc += __shfl_xor(acc, o);
        if (lane == 0) {
            float bias = (r < ACT) ? loadF(ba, r, bf) : loadF(bc, 0, bf);
            float v = acc + bias;
            if (bf) ((__hip_bfloat16*)out)[r] = __float2bfloat16(v);
            else ((float*)out)[r] = v;
        }
    }
}

extern "C" void kernel_launch(void* const* d_in, const int* in_sizes, int n_in,
                              void* d_out, int out_size, void* d_ws, size_t ws_size,
                              hipStream_t stream) {
    const void* x_in = d_in[0];
    const void* edge = d_in[1];
    const void* sc0 = d_in[2];
    const void* sc1 = d_in[3];
    const void* sc2 = d_in[4];
    const void* W1 = d_in[5];
    const void* b1 = d_in[6];
    const void* W2 = d_in[7];
    const void* b2 = d_in[8];
    const void* W3 = d_in[9];
    const void* b3 = d_in[10];
    const void* Wa = d_in[11];
    const void* ba = d_in[12];
    const void* Wc = d_in[13];
    const void* bc = d_in[14];

    char* p = (char*)d_ws;
    auto alloc = [&](size_t bytes) {
        char* r = p;
        p += (bytes + 255) & ~(size_t)255;
        return (void*)r;
    };
    int* flags = (int*)alloc(2 * 4);
    int* cnt = (int*)alloc(NN * 4);
    int* cols = (int*)alloc((size_t)NN * MAXDEG * 4);
    float* wve = (float*)alloc((size_t)NN * MAXDEG * 4);
    float* P0 = (float*)alloc((size_t)NN * 60 * 4);
    float* P1 = (float*)alloc((size_t)NN * 60 * 4);
    u16* P2b = (u16*)alloc((size_t)NN * 60 * 2);
    u16* W60b = (u16*)alloc((size_t)NN * 60 * 2);
    float* Q0 = (float*)alloc((size_t)NN * 30 * 4);
    float* Q1 = (float*)alloc((size_t)NN * 30 * 4);
    u16* Q2b = (u16*)alloc((size_t)NN * 30 * 2);
    u16* W30b = (u16*)alloc((size_t)NN * 30 * 2);
    float* R1 = (float*)alloc(NN * 4);
    float* R2 = (float*)alloc(NN * 4);
    float* Sa = (float*)alloc(NN * 4);
    float* Wv3 = (float*)alloc(NN * 4);
    float* state = (float*)alloc(CONCAT * 4);

    k_prep<<<GB, 256, 0, stream>>>(x_in, W1, Wa, edge, flags, cnt, P0, P1, P2b);
    k_fill<<<GB, 256, 0, stream>>>(edge, flags, cnt, cols);
    k_s1<<<GB, 256, 0, stream>>>(cnt, cols, wve, P1, P2b, W60b);
    k_s2<<<GB, 256, 0, stream>>>(cnt, cols, wve, P0, P2b, W60b, W2, b1, flags, Q0, Q1, Q2b);
    k_s3<<<GB, 256, 0, stream>>>(cnt, cols, wve, Q1, Q2b, W30b);
    k_s4<<<GB, 256, 0, stream>>>(cnt, cols, wve, Q0, Q2b, W30b, W3, b2, flags, R1, R2, Sa);
    k_s5<<<GB, 256, 0, stream>>>(cnt, cols, wve, R1, R2, Wv3);
    k_s6<<<GB, 256, 0, stream>>>(cnt, cols, wve, Sa, Wv3, b3, sc0, sc1, sc2, flags, state);
    k_heads<<<HB, 256, 0, stream>>>(state, Wa, ba, Wc, bc, flags, d_out);
}